// Round 10
// baseline (946.616 us; speedup 1.0000x reference)
//
#include <hip/hip_runtime.h>
#include <cstdint>

#define NPTS 8192
#define NB 8
#define DS 512
#define CF 64
#define KNN 32
#define NFPS 8                        // FPS blocks; TWO instances each (wave-split)
#define NWORK 248
#define NCOSI 64
#define NITEMS (NCOSI + 2 * NB * DS)  // 64 cos chunks + 8192 knn+group items
#define DYNLDS 98304                  // occupancy limiter: 1 block/CU (spin protocol)

typedef float v2f __attribute__((ext_vector_type(2)));
typedef unsigned long long ull;

// ---- DPP wave-64 reductions (VALU only) -----------------------------------
__device__ __forceinline__ float wave_max63(float x) {
  int v;
  v = __builtin_amdgcn_update_dpp(0, __float_as_int(x), 0x111, 0xf, 0xf, true); x = fmaxf(x, __int_as_float(v));
  v = __builtin_amdgcn_update_dpp(0, __float_as_int(x), 0x112, 0xf, 0xf, true); x = fmaxf(x, __int_as_float(v));
  v = __builtin_amdgcn_update_dpp(0, __float_as_int(x), 0x114, 0xf, 0xf, true); x = fmaxf(x, __int_as_float(v));
  v = __builtin_amdgcn_update_dpp(0, __float_as_int(x), 0x118, 0xf, 0xf, true); x = fmaxf(x, __int_as_float(v));
  v = __builtin_amdgcn_update_dpp(0, __float_as_int(x), 0x142, 0xf, 0xf, true); x = fmaxf(x, __int_as_float(v));
  v = __builtin_amdgcn_update_dpp(0, __float_as_int(x), 0x143, 0xf, 0xf, true); x = fmaxf(x, __int_as_float(v));
  return x;  // valid in lane 63
}

__device__ __forceinline__ float wave_sum_bcast(float x) {
  int v;
  v = __builtin_amdgcn_update_dpp(0, __float_as_int(x), 0x111, 0xf, 0xf, true); x += __int_as_float(v);
  v = __builtin_amdgcn_update_dpp(0, __float_as_int(x), 0x112, 0xf, 0xf, true); x += __int_as_float(v);
  v = __builtin_amdgcn_update_dpp(0, __float_as_int(x), 0x114, 0xf, 0xf, true); x += __int_as_float(v);
  v = __builtin_amdgcn_update_dpp(0, __float_as_int(x), 0x118, 0xf, 0xf, true); x += __int_as_float(v);
  v = __builtin_amdgcn_update_dpp(0, __float_as_int(x), 0x142, 0xf, 0xf, true); x += __int_as_float(v);
  v = __builtin_amdgcn_update_dpp(0, __float_as_int(x), 0x143, 0xf, 0xf, true); x += __int_as_float(v);
  return __int_as_float(__builtin_amdgcn_readlane(__float_as_int(x), 63));
}

// zero acc[0..8] + done([13]); idxbuf stays 0xAA-poisoned (>=8192 sentinel).
__global__ __launch_bounds__(64) void zero_kernel(float* __restrict__ acc) {
  if (threadIdx.x < 16) acc[threadIdx.x] = 0.0f;
}

// ONE fused kernel, 256 blocks x 512 thr, dynamic LDS 98.3KB => 1 block/CU =>
// all 256 blocks co-resident => producer/consumer spin deadlock-free.
//   blocks 0..7   : FPS — R20: WAVE-SPLIT DUAL INSTANCE. Evidence: all
//                   barrier-lockstep variants (R3/R4/R6/R7/R9) sit at
//                   467-491us because same-instance waves stall at the same
//                   points (issue+tail sum pinned ~2230cy/iter). Fix at WAVE
//                   granularity (R5's ILP idea without its per-wave instr
//                   doubling): waves 0-3 = instance A, waves 4-7 = instance B;
//                   each SIMD hosts 1 A-wave + 1 B-wave, so A's reduce/sync
//                   tail hides under B's issue and vice versa. NO s_barrier in
//                   the loop: per-wave 64-bit atomic LDS slot carries
//                   (dist | seq<<13 | 8191-e) — tag+payload in one untearable
//                   word; waves poll their group's 4 slots for seq==it+1.
//                   Winner coords fetched from global (L2; hidden by sibling).
//                   Deadlock-free: group waves consume only own-group slots,
//                   written before any poll; parity dbuf safe (bank reuse
//                   requires consuming the intervening iteration).
//   blocks 8..255 : workers with STATIC staggered assignment (R8 lesson).
__global__ __attribute__((amdgpu_waves_per_eu(2, 2))) __launch_bounds__(512)
void fused_kernel(
    const float* __restrict__ logits, const float* __restrict__ logits1,
    const float* __restrict__ p0first, const float* __restrict__ p0sec,
    int* __restrict__ idxbuf, float* __restrict__ acc,
    int* __restrict__ done, float* __restrict__ out) {
  extern __shared__ char smem[];
  __shared__ __align__(16) ull slots[2][2][4];  // [parity][group][gwave]
  __shared__ int wtot[8];
  __shared__ int s_bl[2];
  __shared__ int ctr, eqctr, s_center;
  __shared__ float wloss[8];

  const int blk = blockIdx.x;
  const int t = threadIdx.x;

  if (blk < NFPS) {
    // ========== FPS: two 4-wave instances, seq-tagged slot sync ============
    const int lane = t & 63, wave = t >> 6;
    const int group = wave >> 2;         // 0 = A, 1 = B
    const int gwave = wave & 3;          // wave within instance
    const int inst = blk * 2 + group;    // 0..15 (matches worker 'pair')
    const float* p = ((inst >> 3) ? p0sec : p0first) + (size_t)(inst & 7) * NPTS * 3;
    int* idx_out = idxbuf + inst * DS;
    const int lt = (gwave << 6) | lane;  // 0..255 local tid within instance

    // thread owns points e = lt*32 + j, j=0..31; v2f group g: j=2g (.x), 2g+1 (.y)
    v2f px2[16], py2[16], pz2[16], dist2[16];
    {
      const float4* p4 = (const float4*)p;
#pragma unroll
      for (int k = 0; k < 8; ++k) {
        float4 v0 = p4[lt * 24 + 3 * k + 0];
        float4 v1 = p4[lt * 24 + 3 * k + 1];
        float4 v2 = p4[lt * 24 + 3 * k + 2];
        px2[2 * k]     = (v2f){v0.x, v0.w};
        py2[2 * k]     = (v2f){v0.y, v1.x};
        pz2[2 * k]     = (v2f){v0.z, v1.y};
        px2[2 * k + 1] = (v2f){v1.z, v2.y};
        py2[2 * k + 1] = (v2f){v1.w, v2.z};
        pz2[2 * k + 1] = (v2f){v2.x, v2.w};
        dist2[2 * k] = (v2f){3.4e38f, 3.4e38f};
        dist2[2 * k + 1] = (v2f){3.4e38f, 3.4e38f};
      }
    }
    if (t < 16) ((ull*)slots)[t] = 0ull;  // clear seq tags (LDS undefined)
    if (lt == 0)
      __hip_atomic_store(&idx_out[0], 0, __ATOMIC_RELAXED, __HIP_MEMORY_SCOPE_AGENT);
    float wx = p[0], wy = p[1], wz = p[2];  // seed = point 0
    __syncthreads();  // once, pre-loop: slots cleared before any poll

    for (int it = 0; it < DS - 1; ++it) {
      // loop-carried pin: keep coord/dist arrays register-resident
#pragma unroll
      for (int g = 0; g < 16; ++g) {
        asm("" : "+v"(px2[g]), "+v"(py2[g]), "+v"(pz2[g]), "+v"(dist2[g]));
      }
      v2f wx2 = (v2f){wx, wx}, wy2 = (v2f){wy, wy}, wz2 = (v2f){wz, wz};
#pragma unroll
      for (int g = 0; g < 16; ++g) {
        v2f dx = px2[g] - wx2, dy = py2[g] - wy2, dz = pz2[g] - wz2;
        v2f nd = dx * dx + dy * dy + dz * dz;
        dist2[g] = __builtin_elementwise_min(dist2[g], nd);
      }
      // lane max via balanced tree (fmax exactly assoc/commut -> identical)
      v2f m0 = __builtin_elementwise_max(dist2[0], dist2[1]);
      v2f m1 = __builtin_elementwise_max(dist2[2], dist2[3]);
      v2f m2 = __builtin_elementwise_max(dist2[4], dist2[5]);
      v2f m3 = __builtin_elementwise_max(dist2[6], dist2[7]);
      v2f m4 = __builtin_elementwise_max(dist2[8], dist2[9]);
      v2f m5 = __builtin_elementwise_max(dist2[10], dist2[11]);
      v2f m6 = __builtin_elementwise_max(dist2[12], dist2[13]);
      v2f m7 = __builtin_elementwise_max(dist2[14], dist2[15]);
      v2f n0 = __builtin_elementwise_max(m0, m1);
      v2f n1 = __builtin_elementwise_max(m2, m3);
      v2f n2 = __builtin_elementwise_max(m4, m5);
      v2f n3 = __builtin_elementwise_max(m6, m7);
      v2f o0 = __builtin_elementwise_max(n0, n1);
      v2f o1 = __builtin_elementwise_max(n2, n3);
      v2f q = __builtin_elementwise_max(o0, o1);
      float lm = fmaxf(q.x, q.y);
      // wave max + broadcast
      float wmv = wave_max63(lm);
      float wm = __int_as_float(__builtin_amdgcn_readlane(__float_as_int(wmv), 63));
      // wave tie-break: lowest candidate lane == smallest e (contiguous map)
      ull cmask = __ballot(lm == wm);
      int winlane = (int)__ffsll(cmask) - 1;
      if (lane == winlane) {
        int jbest = 0;
#pragma unroll
        for (int jp = 31; jp >= 0; --jp) {
          float dv = (jp & 1) ? dist2[jp >> 1].y : dist2[jp >> 1].x;
          if (dv == lm) jbest = jp;  // min j achieving lm
        }
        unsigned e_best = ((unsigned)lt << 5) | (unsigned)jbest;
        // key: [63:32]=dist bits, [31:13]=seq=it+1, [12:0]=8191-e.
        // same-iteration keys share seq -> 64-bit compare == (dist, min e).
        ull key = (((ull)__float_as_uint(wm)) << 32) |
                  (((ull)(unsigned)(it + 1)) << 13) | (ull)(8191u - e_best);
        __hip_atomic_store(&slots[it & 1][group][gwave], key, __ATOMIC_RELAXED,
                           __HIP_MEMORY_SCOPE_WORKGROUP);
      }
      // poll own group's 4 slots for this iteration's tag
      const unsigned want = (unsigned)(it + 1);
      ull k0, k1, k2, k3;
      for (;;) {
        k0 = __hip_atomic_load(&slots[it & 1][group][0], __ATOMIC_RELAXED,
                               __HIP_MEMORY_SCOPE_WORKGROUP);
        k1 = __hip_atomic_load(&slots[it & 1][group][1], __ATOMIC_RELAXED,
                               __HIP_MEMORY_SCOPE_WORKGROUP);
        k2 = __hip_atomic_load(&slots[it & 1][group][2], __ATOMIC_RELAXED,
                               __HIP_MEMORY_SCOPE_WORKGROUP);
        k3 = __hip_atomic_load(&slots[it & 1][group][3], __ATOMIC_RELAXED,
                               __HIP_MEMORY_SCOPE_WORKGROUP);
        if ((((unsigned)k0 >> 13) == want) & (((unsigned)k1 >> 13) == want) &
            (((unsigned)k2 >> 13) == want) & (((unsigned)k3 >> 13) == want))
          break;
      }
      ull a0 = k0 > k1 ? k0 : k1, a1 = k2 > k3 ? k2 : k3;
      ull kb = a0 > a1 ? a0 : a1;
      unsigned e = 8191u - (unsigned)(kb & 0x1fffu);
      if (lt == 0)
        __hip_atomic_store(&idx_out[it + 1], (int)e, __ATOMIC_RELAXED,
                           __HIP_MEMORY_SCOPE_AGENT);
      // winner coords from global (L2-hot, uniform); latency hides under the
      // sibling instance's issue stream.
      wx = p[e * 3 + 0]; wy = p[e * 3 + 1]; wz = p[e * 3 + 2];
    }
  } else {
    // ================= worker: static staggered items ======================
    int* hb0 = (int*)smem;                         // [2][2048] = 16 KB
    int* hb1 = (int*)(smem + 16384);               // [2][2048] = 16 KB
    float* Drows = (float*)(smem + 32768);         // [33][64] = 8448 B
    int* nbr = (int*)(smem + 41216);               // [32]
    int* eq = (int*)(smem + 41344);                // [256]
    const int lane = t & 63, wave = t >> 6;
    const int w0 = blk - NFPS;  // 0..247
    for (int item = w0; item < NITEMS; item += NWORK) {
      if (item < NCOSI) {
        // ---- cos chunk: rows item*1024 .. +1023, 2 rows/thread ------------
        float cv = 0.0f;
#pragma unroll
        for (int rr = 0; rr < 2; ++rr) {
          int row = item * 1024 + rr * 512 + t;
          const float4* A = (const float4*)(logits + (size_t)row * CF);
          const float4* Bv = (const float4*)(logits1 + (size_t)row * CF);
          float ab = 0.f, aa = 0.f, bb = 0.f;
#pragma unroll
          for (int i = 0; i < 16; ++i) {
            float4 a = A[i], c4 = Bv[i];
            ab += a.x * c4.x + a.y * c4.y + a.z * c4.z + a.w * c4.w;
            aa += a.x * a.x + a.y * a.y + a.z * a.z + a.w * a.w;
            bb += c4.x * c4.x + c4.y * c4.y + c4.z * c4.z + c4.w * c4.w;
          }
          cv += ab / fmaxf(sqrtf(aa) * sqrtf(bb), 1e-8f);
        }
        cv = wave_sum_bcast(cv);
        if (lane == 0) wloss[wave] = cv;
        __syncthreads();
        if (t == 0) {
          float s = 0.f;
#pragma unroll
          for (int w = 0; w < 8; ++w) s += wloss[w];
          atomicAdd(&acc[0], s);
        }
        __syncthreads();
      } else {
        // ---- knn+group for one query --------------------------------------
        const int qi2 = item - NCOSI;
        const int m = qi2 >> 4, pair = qi2 & 15;
        const int g = pair * DS + m;
        const int view = pair >> 3, b = pair & 7;
        const float* p = (view ? p0sec : p0first) + (size_t)b * NPTS * 3;
        // vectorized point load: 16 consecutive points = 12 dwordx4 / thread
        float f48[48];
        {
          const float4* p4 = (const float4*)p;
#pragma unroll
          for (int i = 0; i < 12; ++i) {
            float4 v4 = p4[t * 12 + i];
            f48[i * 4 + 0] = v4.x; f48[i * 4 + 1] = v4.y;
            f48[i * 4 + 2] = v4.z; f48[i * 4 + 3] = v4.w;
          }
        }
        for (int k = t; k < 4096; k += 512) hb0[k] = 0;
        if (t == 0) {
          int ce;
          while ((unsigned)(ce = __hip_atomic_load(&idxbuf[g], __ATOMIC_RELAXED,
                                                   __HIP_MEMORY_SCOPE_AGENT)) >= 8192u)
            __builtin_amdgcn_s_sleep(2);
          s_center = ce;
        }
        __syncthreads();
        const int ci = s_center;
        const float qx = p[ci * 3], qy = p[ci * 3 + 1], qz = p[ci * 3 + 2];
        const float qq = qx * qx + qy * qy + qz * qz;
        const int cpy = (t & 1) << 11;  // histogram copy (2 copies)
        unsigned sk[16];  // keys for points e = t*16 + j
#pragma unroll
        for (int j = 0; j < 16; ++j) {
          float sx = f48[j * 3], sy = f48[j * 3 + 1], sz = f48[j * 3 + 2];
          float ss = sx * sx + sy * sy + sz * sz;
          float dt = qx * sx + qy * sy + qz * sz;
          float d = qq + ss - 2.0f * dt;  // same formula as reference
          unsigned u = __float_as_uint(d);
          u = (u & 0x80000000u) ? ~u : (u | 0x80000000u);  // sortable
          sk[j] = u;
        }
        int rrank = 31;
        // ---- pass A: top 11 bits, 2048 bins -------------------------------
#pragma unroll
        for (int j = 0; j < 16; ++j) atomicAdd(&hb0[cpy + (sk[j] >> 21)], 1);
        __syncthreads();
        unsigned pA, pAB, V;
        {
          int b0 = t << 2;
          int c0 = hb0[b0] + hb0[2048 + b0];
          int c1 = hb0[b0 + 1] + hb0[2048 + b0 + 1];
          int c2 = hb0[b0 + 2] + hb0[2048 + b0 + 2];
          int c3 = hb0[b0 + 3] + hb0[2048 + b0 + 3];
          int s = c0 + c1 + c2 + c3;
          int inc = s;
#pragma unroll
          for (int o = 1; o < 64; o <<= 1) {
            int v = __shfl_up(inc, o, 64);
            if (lane >= o) inc += v;
          }
          if (lane == 63) wtot[wave] = inc;
          for (int k = t; k < 4096; k += 512) hb1[k] = 0;  // zero B during scan
          __syncthreads();
          int off = 0;
#pragma unroll
          for (int w = 0; w < 8; ++w) off += (w < wave) ? wtot[w] : 0;
          int exc = off + inc - s;
          if (rrank >= exc && rrank < exc + s) {
            int r2 = rrank - exc; int bin, less;
            if (r2 < c0) { bin = 0; less = 0; }
            else if (r2 < c0 + c1) { bin = 1; less = c0; }
            else if (r2 < c0 + c1 + c2) { bin = 2; less = c0 + c1; }
            else { bin = 3; less = c0 + c1 + c2; }
            s_bl[0] = b0 + bin; s_bl[1] = exc + less;
          }
          __syncthreads();
          pA = (unsigned)s_bl[0];
          rrank -= s_bl[1];
        }
        // ---- pass B: bits [20:10], 2048 bins ------------------------------
#pragma unroll
        for (int j = 0; j < 16; ++j) {
          unsigned u = sk[j];
          if ((u >> 21) == pA) atomicAdd(&hb1[cpy + ((u >> 10) & 2047)], 1);
        }
        __syncthreads();
        {
          int b0 = t << 2;
          int c0 = hb1[b0] + hb1[2048 + b0];
          int c1 = hb1[b0 + 1] + hb1[2048 + b0 + 1];
          int c2 = hb1[b0 + 2] + hb1[2048 + b0 + 2];
          int c3 = hb1[b0 + 3] + hb1[2048 + b0 + 3];
          int s = c0 + c1 + c2 + c3;
          int inc = s;
#pragma unroll
          for (int o = 1; o < 64; o <<= 1) {
            int v = __shfl_up(inc, o, 64);
            if (lane >= o) inc += v;
          }
          if (lane == 63) wtot[wave] = inc;
          for (int k = t; k < 4096; k += 512) hb0[k] = 0;  // zero C buf
          __syncthreads();
          int off = 0;
#pragma unroll
          for (int w = 0; w < 8; ++w) off += (w < wave) ? wtot[w] : 0;
          int exc = off + inc - s;
          if (rrank >= exc && rrank < exc + s) {
            int r2 = rrank - exc; int bin, less;
            if (r2 < c0) { bin = 0; less = 0; }
            else if (r2 < c0 + c1) { bin = 1; less = c0; }
            else if (r2 < c0 + c1 + c2) { bin = 2; less = c0 + c1; }
            else { bin = 3; less = c0 + c1 + c2; }
            s_bl[0] = b0 + bin; s_bl[1] = exc + less;
          }
          __syncthreads();
          pAB = (pA << 11) | (unsigned)s_bl[0];
          rrank -= s_bl[1];
        }
        // ---- pass C: bits [9:0], 1024 bins --------------------------------
        const int cpyC = (t & 1) << 10;
#pragma unroll
        for (int j = 0; j < 16; ++j) {
          unsigned u = sk[j];
          if ((u >> 10) == pAB) atomicAdd(&hb0[cpyC + (u & 1023)], 1);
        }
        __syncthreads();
        {
          int b0 = t << 1;
          int c0 = hb0[b0] + hb0[1024 + b0];
          int c1 = hb0[b0 + 1] + hb0[1024 + b0 + 1];
          int s = c0 + c1;
          int inc = s;
#pragma unroll
          for (int o = 1; o < 64; o <<= 1) {
            int v = __shfl_up(inc, o, 64);
            if (lane >= o) inc += v;
          }
          if (lane == 63) wtot[wave] = inc;
          __syncthreads();
          int off = 0;
#pragma unroll
          for (int w = 0; w < 8; ++w) off += (w < wave) ? wtot[w] : 0;
          int exc = off + inc - s;
          if (rrank >= exc && rrank < exc + s) {
            int r2 = rrank - exc;
            if (r2 < c0) { s_bl[0] = b0; s_bl[1] = exc; }
            else { s_bl[0] = b0 + 1; s_bl[1] = exc + c0; }
          }
          if (t == 0) { ctr = 0; eqctr = 0; }  // folded init (was own barrier)
          __syncthreads();
          V = (pAB << 10) | (unsigned)s_bl[0];
          rrank -= s_bl[1];
        }
        // ---- output set: keys < V, plus (rrank+1) smallest-index == V -----
#pragma unroll
        for (int j = 0; j < 16; ++j) {
          unsigned u = sk[j];
          if (u < V) {
            int s = atomicAdd(&ctr, 1);
            nbr[s] = t * 16 + j;
          } else if (u == V) {
            int s2 = atomicAdd(&eqctr, 1);
            if (s2 < 256) eq[s2] = t * 16 + j;
          }
        }
        __syncthreads();
        if (t == 0) {
          int need = rrank + 1;
          int E = eqctr; if (E > 256) E = 256;
          int base = KNN - need;
          for (int s = 0; s < need; ++s) {
            int mi = 0;
            for (int i = 1; i < E; ++i)
              if (eq[i] < eq[mi]) mi = i;
            nbr[base + s] = eq[mi];
            eq[mi] = 0x7fffffff;
          }
        }
        __syncthreads();
        // ---- group loss (rows 0..31 = neighbors, row 32 = center) ---------
        const float* f = (view ? logits1 : logits) + (size_t)b * NPTS * CF;
        for (int r = wave; r < 33; r += 8) {
          int e = (r < 32) ? nbr[r] : ci;
          Drows[r * 64 + lane] = f[(size_t)e * CF + lane];
        }
        __syncthreads();
        float avg = 0.0f;
#pragma unroll
        for (int r = 0; r < 33; ++r) avg += Drows[r * 64 + lane];
        avg *= (1.0f / 33.0f);
        float na = wave_sum_bcast(avg * avg);
        const float rsna = sqrtf(na);
        float loss = 0.0f;
        for (int r = wave; r < 33; r += 8) {
          float d = Drows[r * 64 + lane];
          float d0 = wave_sum_bcast(d * avg);
          float n0 = wave_sum_bcast(d * d);
          float den = fmaxf(sqrtf(n0) * rsna, 1e-8f);
          loss += -200.0f * (d0 / den) - 0.5f * log1pf(40.0f * n0);
        }
        if (lane == 0) wloss[wave] = loss;
        __syncthreads();
        if (t == 0) {
          float s = 0.f;
#pragma unroll
          for (int w = 0; w < 8; ++w) s += wloss[w];
          atomicAdd(&acc[1 + b], s * (1.0f / 33.0f));
        }
        __syncthreads();
      }
    }
    // ---- completion + last-block finalize --------------------------------
    __syncthreads();
    if (t == 0) {
      int d = __hip_atomic_fetch_add(done, 1, __ATOMIC_ACQ_REL, __HIP_MEMORY_SCOPE_AGENT);
      if (d == NWORK - 1) {
        float a0 = __hip_atomic_load(&acc[0], __ATOMIC_ACQUIRE, __HIP_MEMORY_SCOPE_AGENT);
        float gsum = 0.0f;
        for (int bb = 0; bb < 8; ++bb) {
          float Sb = __hip_atomic_load(&acc[1 + bb], __ATOMIC_ACQUIRE, __HIP_MEMORY_SCOPE_AGENT);
          gsum = (gsum + Sb) * (1.0f / 512.0f);  // /512 exact (pow2)
        }
        gsum *= 0.125f;  // / b
        out[0] = -a0 / 65536.0f + gsum + gsum;
      }
    }
  }
}

extern "C" void kernel_launch(void* const* d_in, const int* in_sizes, int n_in,
                              void* d_out, int out_size, void* d_ws, size_t ws_size,
                              hipStream_t stream) {
  (void)in_sizes; (void)n_in; (void)out_size; (void)ws_size;
  const float* logits  = (const float*)d_in[0];
  const float* logits1 = (const float*)d_in[1];
  const float* p0first = (const float*)d_in[2];
  const float* p0sec   = (const float*)d_in[3];
  float* out = (float*)d_out;

  float* acc = (float*)d_ws;           // [0]=cosSum, [1..8]=S[b], [13]=done
  int* done  = (int*)d_ws + 13;
  int* idxbuf = (int*)d_ws + 16;       // [2*8*512]; 0xAA poison = "unpublished"

  zero_kernel<<<1, 64, 0, stream>>>(acc);
  fused_kernel<<<NFPS + NWORK, 512, DYNLDS, stream>>>(logits, logits1, p0first, p0sec,
                                                      idxbuf, acc, done, out);
}

// Round 13
// 522.274 us; speedup vs baseline: 1.8125x; 1.8125x over previous
//
#include <hip/hip_runtime.h>
#include <cstdint>

#define NPTS 8192
#define NB 8
#define DS 512
#define CF 64
#define KNN 32
#define NFPS 16
#define NWORK 240
#define NCOSI 64
#define NITEMS (NCOSI + 2 * NB * DS)  // 64 cos chunks + 8192 knn+group items
#define DYNLDS 98304                  // max(fps ldsP 96KB, worker bufs ~42KB)

typedef float v2f __attribute__((ext_vector_type(2)));
typedef unsigned long long ull;

// ---- DPP wave-64 reductions (VALU only) -----------------------------------
__device__ __forceinline__ float wave_max63(float x) {
  int v;
  v = __builtin_amdgcn_update_dpp(0, __float_as_int(x), 0x111, 0xf, 0xf, true); x = fmaxf(x, __int_as_float(v));
  v = __builtin_amdgcn_update_dpp(0, __float_as_int(x), 0x112, 0xf, 0xf, true); x = fmaxf(x, __int_as_float(v));
  v = __builtin_amdgcn_update_dpp(0, __float_as_int(x), 0x114, 0xf, 0xf, true); x = fmaxf(x, __int_as_float(v));
  v = __builtin_amdgcn_update_dpp(0, __float_as_int(x), 0x118, 0xf, 0xf, true); x = fmaxf(x, __int_as_float(v));
  v = __builtin_amdgcn_update_dpp(0, __float_as_int(x), 0x142, 0xf, 0xf, true); x = fmaxf(x, __int_as_float(v));
  v = __builtin_amdgcn_update_dpp(0, __float_as_int(x), 0x143, 0xf, 0xf, true); x = fmaxf(x, __int_as_float(v));
  return x;  // valid in lane 63
}

__device__ __forceinline__ float wave_sum_bcast(float x) {
  int v;
  v = __builtin_amdgcn_update_dpp(0, __float_as_int(x), 0x111, 0xf, 0xf, true); x += __int_as_float(v);
  v = __builtin_amdgcn_update_dpp(0, __float_as_int(x), 0x112, 0xf, 0xf, true); x += __int_as_float(v);
  v = __builtin_amdgcn_update_dpp(0, __float_as_int(x), 0x114, 0xf, 0xf, true); x += __int_as_float(v);
  v = __builtin_amdgcn_update_dpp(0, __float_as_int(x), 0x118, 0xf, 0xf, true); x += __int_as_float(v);
  v = __builtin_amdgcn_update_dpp(0, __float_as_int(x), 0x142, 0xf, 0xf, true); x += __int_as_float(v);
  v = __builtin_amdgcn_update_dpp(0, __float_as_int(x), 0x143, 0xf, 0xf, true); x += __int_as_float(v);
  return __int_as_float(__builtin_amdgcn_readlane(__float_as_int(x), 63));
}

// zero acc[0..8] + done([13]); idxbuf stays 0xAA-poisoned (>=8192 sentinel).
__global__ __launch_bounds__(64) void zero_kernel(float* __restrict__ acc) {
  if (threadIdx.x < 16) acc[threadIdx.x] = 0.0f;
}

// ONE fused kernel, 256 blocks x 512 thr, dynamic LDS 98.3KB => 1 block/CU =>
// all 256 blocks co-resident => producer/consumer spin deadlock-free.
//   blocks 0..15  : FPS — R21 (3rd submit; R11/R12 were infra failures —
//                   "container failed twice", no compile/correctness signal;
//                   delta vs known-good R8 is branch-hoisted register
//                   arithmetic only): R8 base (best measured, 466-470us) +
//                   HOISTED jbest scan. The 16-step scan depends only on
//                   (lm, dist2) — ready BEFORE the DPP chain — but sat inside
//                   the winlane branch, serializing after DPP+readlane+ballot.
//                   Hoisted, its ~35 instrs fill the DPP chain's hazard
//                   bubbles; the winlane branch is now a single slot write.
//   blocks 16..255: workers with STATIC staggered assignment (R8 lesson).
__global__ __launch_bounds__(512, 2) void fused_kernel(
    const float* __restrict__ logits, const float* __restrict__ logits1,
    const float* __restrict__ p0first, const float* __restrict__ p0sec,
    int* __restrict__ idxbuf, float* __restrict__ acc,
    int* __restrict__ done, float* __restrict__ out) {
  extern __shared__ char smem[];
  __shared__ __align__(16) ull wslot[2][8];
  __shared__ int wtot[8];
  __shared__ int s_bl[2];
  __shared__ int ctr, eqctr, s_center;
  __shared__ float wloss[8];

  const int blk = blockIdx.x;
  const int t = threadIdx.x;

  if (blk < NFPS) {
    // ================= FPS (8 waves, 1 raw barrier/iter) ===================
    float* ldsP = (float*)smem;  // 96 KB winner-lookup table (linear copy of p)
    const int view = blk >> 3, b = blk & 7;
    const float* p = (view ? p0sec : p0first) + (size_t)b * NPTS * 3;
    int* idx_out = idxbuf + blk * DS;
    const int lane = t & 63, wave = t >> 6;
    // lane-contiguous mapping: thread t owns points e = t*16 + j, j = 0..15;
    // v2f group g holds j = 2g (.x) and j = 2g+1 (.y).
    v2f px2[8], py2[8], pz2[8], dist2[8];
    {
      float f48[48];
      const float4* p4 = (const float4*)p;
      float4* l4 = (float4*)ldsP;
#pragma unroll
      for (int i = 0; i < 12; ++i) {
        float4 v4 = p4[t * 12 + i];
        l4[t * 12 + i] = v4;  // ldsP[q] == p[q]
        f48[i * 4 + 0] = v4.x; f48[i * 4 + 1] = v4.y;
        f48[i * 4 + 2] = v4.z; f48[i * 4 + 3] = v4.w;
      }
#pragma unroll
      for (int g = 0; g < 8; ++g) {
        px2[g] = (v2f){f48[6 * g + 0], f48[6 * g + 3]};
        py2[g] = (v2f){f48[6 * g + 1], f48[6 * g + 4]};
        pz2[g] = (v2f){f48[6 * g + 2], f48[6 * g + 5]};
        dist2[g] = (v2f){3.4e38f, 3.4e38f};
      }
    }
    if (t == 0)
      __hip_atomic_store(&idx_out[0], 0, __ATOMIC_RELAXED, __HIP_MEMORY_SCOPE_AGENT);
    float wx = p[0], wy = p[1], wz = p[2];  // seed = point 0
    __syncthreads();  // once; staging drain is fine here

    for (int it = 0; it < DS - 1; ++it) {
      // loop-carried pin (R18): keeps coord/dist arrays register-resident.
#pragma unroll
      for (int g = 0; g < 8; ++g) {
        asm("" : "+v"(px2[g]), "+v"(py2[g]), "+v"(pz2[g]), "+v"(dist2[g]));
      }
      v2f wx2 = (v2f){wx, wx}, wy2 = (v2f){wy, wy}, wz2 = (v2f){wz, wz};
#pragma unroll
      for (int g = 0; g < 8; ++g) {
        v2f dx = px2[g] - wx2, dy = py2[g] - wy2, dz = pz2[g] - wz2;
        v2f nd = dx * dx + dy * dy + dz * dz;
        dist2[g] = __builtin_elementwise_min(dist2[g], nd);
      }
      // lane max via balanced tree (fmax exactly assoc/commut -> identical)
      v2f m0 = __builtin_elementwise_max(dist2[0], dist2[1]);
      v2f m1 = __builtin_elementwise_max(dist2[2], dist2[3]);
      v2f m2 = __builtin_elementwise_max(dist2[4], dist2[5]);
      v2f m3 = __builtin_elementwise_max(dist2[6], dist2[7]);
      v2f n0 = __builtin_elementwise_max(m0, m1);
      v2f n1 = __builtin_elementwise_max(m2, m3);
      v2f q = __builtin_elementwise_max(n0, n1);
      float lm = fmaxf(q.x, q.y);
      // jbest scan HOISTED (depends only on lm/dist2): overlaps the DPP
      // chain's hazard bubbles instead of serializing after ballot.
      int jbest = 0;
#pragma unroll
      for (int jp = 15; jp >= 0; --jp) {
        float dv = (jp & 1) ? dist2[jp >> 1].y : dist2[jp >> 1].x;
        if (dv == lm) jbest = jp;  // min j achieving lm
      }
      unsigned e_best = ((unsigned)t << 4) | (unsigned)jbest;
      // wave max + broadcast
      float wmv = wave_max63(lm);
      float wm = __int_as_float(__builtin_amdgcn_readlane(__float_as_int(wmv), 63));
      // wave tie-break: lowest candidate lane == smallest e (contiguous map)
      ull cmask = __ballot(lm == wm);
      int winlane = (int)__ffsll(cmask) - 1;
      if (lane == winlane)
        wslot[it & 1][wave] =
            (((ull)__float_as_uint(wm)) << 32) | (ull)(8191u - e_best);
      // RAW barrier: drain LDS only; the idx publish store stays in flight.
      asm volatile("s_waitcnt lgkmcnt(0)\n\ts_barrier" ::: "memory");
      {
        const ull* ws = wslot[it & 1];
        ull k0 = ws[0], k1 = ws[1], k2 = ws[2], k3 = ws[3];
        ull k4 = ws[4], k5 = ws[5], k6 = ws[6], k7 = ws[7];
        ull a0 = k0 > k1 ? k0 : k1, a1 = k2 > k3 ? k2 : k3;
        ull a2 = k4 > k5 ? k4 : k5, a3 = k6 > k7 ? k6 : k7;
        ull b0 = a0 > a1 ? a0 : a1, b1 = a2 > a3 ? a2 : a3;
        ull kb = b0 > b1 ? b0 : b1;
        unsigned e = 8191u - (unsigned)(kb & 0xffffffffu);
        if (t == 0)
          __hip_atomic_store(&idx_out[it + 1], (int)e, __ATOMIC_RELAXED,
                             __HIP_MEMORY_SCOPE_AGENT);
        wx = ldsP[e * 3 + 0]; wy = ldsP[e * 3 + 1]; wz = ldsP[e * 3 + 2];
      }
    }
  } else {
    // ================= worker: static staggered items ======================
    int* hb0 = (int*)smem;                         // [2][2048] = 16 KB
    int* hb1 = (int*)(smem + 16384);               // [2][2048] = 16 KB
    float* Drows = (float*)(smem + 32768);         // [33][64] = 8448 B
    int* nbr = (int*)(smem + 41216);               // [32]
    int* eq = (int*)(smem + 41344);                // [256]
    const int lane = t & 63, wave = t >> 6;
    const int w0 = blk - NFPS;  // 0..239
    for (int item = w0; item < NITEMS; item += NWORK) {
      if (item < NCOSI) {
        // ---- cos chunk: rows item*1024 .. +1023, 2 rows/thread ------------
        float cv = 0.0f;
#pragma unroll
        for (int rr = 0; rr < 2; ++rr) {
          int row = item * 1024 + rr * 512 + t;
          const float4* A = (const float4*)(logits + (size_t)row * CF);
          const float4* Bv = (const float4*)(logits1 + (size_t)row * CF);
          float ab = 0.f, aa = 0.f, bb = 0.f;
#pragma unroll
          for (int i = 0; i < 16; ++i) {
            float4 a = A[i], c4 = Bv[i];
            ab += a.x * c4.x + a.y * c4.y + a.z * c4.z + a.w * c4.w;
            aa += a.x * a.x + a.y * a.y + a.z * a.z + a.w * a.w;
            bb += c4.x * c4.x + c4.y * c4.y + c4.z * c4.z + c4.w * c4.w;
          }
          cv += ab / fmaxf(sqrtf(aa) * sqrtf(bb), 1e-8f);
        }
        cv = wave_sum_bcast(cv);
        if (lane == 0) wloss[wave] = cv;
        __syncthreads();
        if (t == 0) {
          float s = 0.f;
#pragma unroll
          for (int w = 0; w < 8; ++w) s += wloss[w];
          atomicAdd(&acc[0], s);
        }
        __syncthreads();
      } else {
        // ---- knn+group for one query --------------------------------------
        const int qi2 = item - NCOSI;
        const int m = qi2 >> 4, pair = qi2 & 15;
        const int g = pair * DS + m;
        const int view = pair >> 3, b = pair & 7;
        const float* p = (view ? p0sec : p0first) + (size_t)b * NPTS * 3;
        // vectorized point load: 16 consecutive points = 12 dwordx4 / thread
        float f48[48];
        {
          const float4* p4 = (const float4*)p;
#pragma unroll
          for (int i = 0; i < 12; ++i) {
            float4 v4 = p4[t * 12 + i];
            f48[i * 4 + 0] = v4.x; f48[i * 4 + 1] = v4.y;
            f48[i * 4 + 2] = v4.z; f48[i * 4 + 3] = v4.w;
          }
        }
        for (int k = t; k < 4096; k += 512) hb0[k] = 0;
        if (t == 0) {
          int ce;
          while ((unsigned)(ce = __hip_atomic_load(&idxbuf[g], __ATOMIC_RELAXED,
                                                   __HIP_MEMORY_SCOPE_AGENT)) >= 8192u)
            __builtin_amdgcn_s_sleep(2);
          s_center = ce;
        }
        __syncthreads();
        const int ci = s_center;
        const float qx = p[ci * 3], qy = p[ci * 3 + 1], qz = p[ci * 3 + 2];
        const float qq = qx * qx + qy * qy + qz * qz;
        const int cpy = (t & 1) << 11;  // histogram copy (2 copies)
        unsigned sk[16];  // keys for points e = t*16 + j
#pragma unroll
        for (int j = 0; j < 16; ++j) {
          float sx = f48[j * 3], sy = f48[j * 3 + 1], sz = f48[j * 3 + 2];
          float ss = sx * sx + sy * sy + sz * sz;
          float dt = qx * sx + qy * sy + qz * sz;
          float d = qq + ss - 2.0f * dt;  // same formula as reference
          unsigned u = __float_as_uint(d);
          u = (u & 0x80000000u) ? ~u : (u | 0x80000000u);  // sortable
          sk[j] = u;
        }
        int rrank = 31;
        // ---- pass A: top 11 bits, 2048 bins -------------------------------
#pragma unroll
        for (int j = 0; j < 16; ++j) atomicAdd(&hb0[cpy + (sk[j] >> 21)], 1);
        __syncthreads();
        unsigned pA, pAB, V;
        {
          int b0 = t << 2;
          int c0 = hb0[b0] + hb0[2048 + b0];
          int c1 = hb0[b0 + 1] + hb0[2048 + b0 + 1];
          int c2 = hb0[b0 + 2] + hb0[2048 + b0 + 2];
          int c3 = hb0[b0 + 3] + hb0[2048 + b0 + 3];
          int s = c0 + c1 + c2 + c3;
          int inc = s;
#pragma unroll
          for (int o = 1; o < 64; o <<= 1) {
            int v = __shfl_up(inc, o, 64);
            if (lane >= o) inc += v;
          }
          if (lane == 63) wtot[wave] = inc;
          for (int k = t; k < 4096; k += 512) hb1[k] = 0;  // zero B during scan
          __syncthreads();
          int off = 0;
#pragma unroll
          for (int w = 0; w < 8; ++w) off += (w < wave) ? wtot[w] : 0;
          int exc = off + inc - s;
          if (rrank >= exc && rrank < exc + s) {
            int r2 = rrank - exc; int bin, less;
            if (r2 < c0) { bin = 0; less = 0; }
            else if (r2 < c0 + c1) { bin = 1; less = c0; }
            else if (r2 < c0 + c1 + c2) { bin = 2; less = c0 + c1; }
            else { bin = 3; less = c0 + c1 + c2; }
            s_bl[0] = b0 + bin; s_bl[1] = exc + less;
          }
          __syncthreads();
          pA = (unsigned)s_bl[0];
          rrank -= s_bl[1];
        }
        // ---- pass B: bits [20:10], 2048 bins ------------------------------
#pragma unroll
        for (int j = 0; j < 16; ++j) {
          unsigned u = sk[j];
          if ((u >> 21) == pA) atomicAdd(&hb1[cpy + ((u >> 10) & 2047)], 1);
        }
        __syncthreads();
        {
          int b0 = t << 2;
          int c0 = hb1[b0] + hb1[2048 + b0];
          int c1 = hb1[b0 + 1] + hb1[2048 + b0 + 1];
          int c2 = hb1[b0 + 2] + hb1[2048 + b0 + 2];
          int c3 = hb1[b0 + 3] + hb1[2048 + b0 + 3];
          int s = c0 + c1 + c2 + c3;
          int inc = s;
#pragma unroll
          for (int o = 1; o < 64; o <<= 1) {
            int v = __shfl_up(inc, o, 64);
            if (lane >= o) inc += v;
          }
          if (lane == 63) wtot[wave] = inc;
          for (int k = t; k < 4096; k += 512) hb0[k] = 0;  // zero C buf
          __syncthreads();
          int off = 0;
#pragma unroll
          for (int w = 0; w < 8; ++w) off += (w < wave) ? wtot[w] : 0;
          int exc = off + inc - s;
          if (rrank >= exc && rrank < exc + s) {
            int r2 = rrank - exc; int bin, less;
            if (r2 < c0) { bin = 0; less = 0; }
            else if (r2 < c0 + c1) { bin = 1; less = c0; }
            else if (r2 < c0 + c1 + c2) { bin = 2; less = c0 + c1; }
            else { bin = 3; less = c0 + c1 + c2; }
            s_bl[0] = b0 + bin; s_bl[1] = exc + less;
          }
          __syncthreads();
          pAB = (pA << 11) | (unsigned)s_bl[0];
          rrank -= s_bl[1];
        }
        // ---- pass C: bits [9:0], 1024 bins --------------------------------
        const int cpyC = (t & 1) << 10;
#pragma unroll
        for (int j = 0; j < 16; ++j) {
          unsigned u = sk[j];
          if ((u >> 10) == pAB) atomicAdd(&hb0[cpyC + (u & 1023)], 1);
        }
        __syncthreads();
        {
          int b0 = t << 1;
          int c0 = hb0[b0] + hb0[1024 + b0];
          int c1 = hb0[b0 + 1] + hb0[1024 + b0 + 1];
          int s = c0 + c1;
          int inc = s;
#pragma unroll
          for (int o = 1; o < 64; o <<= 1) {
            int v = __shfl_up(inc, o, 64);
            if (lane >= o) inc += v;
          }
          if (lane == 63) wtot[wave] = inc;
          __syncthreads();
          int off = 0;
#pragma unroll
          for (int w = 0; w < 8; ++w) off += (w < wave) ? wtot[w] : 0;
          int exc = off + inc - s;
          if (rrank >= exc && rrank < exc + s) {
            int r2 = rrank - exc;
            if (r2 < c0) { s_bl[0] = b0; s_bl[1] = exc; }
            else { s_bl[0] = b0 + 1; s_bl[1] = exc + c0; }
          }
          if (t == 0) { ctr = 0; eqctr = 0; }  // folded init (was own barrier)
          __syncthreads();
          V = (pAB << 10) | (unsigned)s_bl[0];
          rrank -= s_bl[1];
        }
        // ---- output set: keys < V, plus (rrank+1) smallest-index == V -----
#pragma unroll
        for (int j = 0; j < 16; ++j) {
          unsigned u = sk[j];
          if (u < V) {
            int s = atomicAdd(&ctr, 1);
            nbr[s] = t * 16 + j;
          } else if (u == V) {
            int s2 = atomicAdd(&eqctr, 1);
            if (s2 < 256) eq[s2] = t * 16 + j;
          }
        }
        __syncthreads();
        if (t == 0) {
          int need = rrank + 1;
          int E = eqctr; if (E > 256) E = 256;
          int base = KNN - need;
          for (int s = 0; s < need; ++s) {
            int mi = 0;
            for (int i = 1; i < E; ++i)
              if (eq[i] < eq[mi]) mi = i;
            nbr[base + s] = eq[mi];
            eq[mi] = 0x7fffffff;
          }
        }
        __syncthreads();
        // ---- group loss (rows 0..31 = neighbors, row 32 = center) ---------
        const float* f = (view ? logits1 : logits) + (size_t)b * NPTS * CF;
        for (int r = wave; r < 33; r += 8) {
          int e = (r < 32) ? nbr[r] : ci;
          Drows[r * 64 + lane] = f[(size_t)e * CF + lane];
        }
        __syncthreads();
        float avg = 0.0f;
#pragma unroll
        for (int r = 0; r < 33; ++r) avg += Drows[r * 64 + lane];
        avg *= (1.0f / 33.0f);
        float na = wave_sum_bcast(avg * avg);
        const float rsna = sqrtf(na);
        float loss = 0.0f;
        for (int r = wave; r < 33; r += 8) {
          float d = Drows[r * 64 + lane];
          float d0 = wave_sum_bcast(d * avg);
          float n0 = wave_sum_bcast(d * d);
          float den = fmaxf(sqrtf(n0) * rsna, 1e-8f);
          loss += -200.0f * (d0 / den) - 0.5f * log1pf(40.0f * n0);
        }
        if (lane == 0) wloss[wave] = loss;
        __syncthreads();
        if (t == 0) {
          float s = 0.f;
#pragma unroll
          for (int w = 0; w < 8; ++w) s += wloss[w];
          atomicAdd(&acc[1 + b], s * (1.0f / 33.0f));
        }
        __syncthreads();
      }
    }
    // ---- completion + last-block finalize --------------------------------
    __syncthreads();
    if (t == 0) {
      int d = __hip_atomic_fetch_add(done, 1, __ATOMIC_ACQ_REL, __HIP_MEMORY_SCOPE_AGENT);
      if (d == NWORK - 1) {
        float a0 = __hip_atomic_load(&acc[0], __ATOMIC_ACQUIRE, __HIP_MEMORY_SCOPE_AGENT);
        float gsum = 0.0f;
        for (int bb = 0; bb < 8; ++bb) {
          float Sb = __hip_atomic_load(&acc[1 + bb], __ATOMIC_ACQUIRE, __HIP_MEMORY_SCOPE_AGENT);
          gsum = (gsum + Sb) * (1.0f / 512.0f);  // /512 exact (pow2)
        }
        gsum *= 0.125f;  // / b
        out[0] = -a0 / 65536.0f + gsum + gsum;
      }
    }
  }
}

extern "C" void kernel_launch(void* const* d_in, const int* in_sizes, int n_in,
                              void* d_out, int out_size, void* d_ws, size_t ws_size,
                              hipStream_t stream) {
  (void)in_sizes; (void)n_in; (void)out_size; (void)ws_size;
  const float* logits  = (const float*)d_in[0];
  const float* logits1 = (const float*)d_in[1];
  const float* p0first = (const float*)d_in[2];
  const float* p0sec   = (const float*)d_in[3];
  float* out = (float*)d_out;

  float* acc = (float*)d_ws;           // [0]=cosSum, [1..8]=S[b], [13]=done
  int* done  = (int*)d_ws + 13;
  int* idxbuf = (int*)d_ws + 16;       // [2*8*512]; 0xAA poison = "unpublished"

  zero_kernel<<<1, 64, 0, stream>>>(acc);
  fused_kernel<<<NFPS + NWORK, 512, DYNLDS, stream>>>(logits, logits1, p0first, p0sec,
                                                      idxbuf, acc, done, out);
}